// Round 7
// baseline (599.337 us; speedup 1.0000x reference)
//
#include <hip/hip_runtime.h>

// RelativePosition: out[b,i,j,:] = (W[clip(ri[b,j]-ri[b,i],-32,32)+33] + bias) * (m[b,i]*m[b,j])
// B=2, L=768, C_Z=128. Output 604 MB f32 -> store-BW bound (~96 us @ 6.3 TB/s).
//
// R5 diagnostic: harness fixed cost ~480 us/replay; kernel-true R6 = ~118 us (5.1 TB/s).
// R6 -> R7: clean NT-store A/B on the good structure. Output is write-once,
// never re-read -> nontemporal stores skip L2 write-allocate (which otherwise
// churns all 32 MB of L2 against the freshly-poisoned dirty lines). R2's NT
// datapoint was confounded by div-heavy grid-stride; this isolates NT.

constexpr int BINS = 32;
constexpr int CZ   = 128;
constexpr int NC   = 2 * BINS + 2;   // 66
constexpr int B_   = 2;
constexpr int L_   = 768;
constexpr int NBLK = B_ * L_;        // 1536: one block per output row [b,i]

typedef float vfloat4 __attribute__((ext_vector_type(4)));

__device__ __forceinline__ void nt_store(float* p, vfloat4 v) {
    __builtin_nontemporal_store(v, (vfloat4*)p);
}

__global__ __launch_bounds__(256) void relpos_kernel(
    const int*  __restrict__ residue_index,   // [B,L] int32
    const void* __restrict__ residue_mask,    // [B,L] bool (byte or int32 layout, detected)
    const float* __restrict__ W,              // [NC, CZ]
    const float* __restrict__ bias,           // [CZ]
    float* __restrict__ out)                  // [B,L,L,CZ]
{
    __shared__ int   ridx_row[L_];    // 3 KB
    __shared__ float mask_row[L_];    // 3 KB
    __shared__ int   s_cnt[3];        // jlo, jend, #mask-ones

    const int tid = threadIdx.x;
    const int row = blockIdx.x;       // b*L + i
    const int b   = row / L_;
    const int i   = row - b * L_;
    const int o   = b * L_;

    const int group = tid >> 5;       // 0..7: one 32-lane group per (i,j) pair
    const int lane  = tid & 31;       // 16 B per lane -> 512 B per pair

    // Detect mask layout (wave-uniform, L2-cached).
    const unsigned int v0 = *(const unsigned int*)residue_mask;
    const bool byte_layout = (v0 & 0xFFFFFF00u) != 0u;

    // Saturated-row values straight from global (L2-hot, once per block).
    const vfloat4* W4 = (const vfloat4*)W;
    const vfloat4 b4  = ((const vfloat4*)bias)[lane];
    const vfloat4 vlo = W4[1 * (CZ / 4) + lane] + b4;         // idx==1
    const vfloat4 vhi = W4[(NC - 1) * (CZ / 4) + lane] + b4;  // idx==65

    if (tid < 3) s_cnt[tid] = 0;
    for (int k = tid; k < L_; k += 256) {
        ridx_row[k] = residue_index[o + k];
        int m = byte_layout ? (int)((const unsigned char*)residue_mask)[o + k]
                            : ((const int*)residue_mask)[o + k];
        mask_row[k] = m ? 1.0f : 0.0f;
    }
    __syncthreads();

    const int   ri_i = ridx_row[i];
    const float m_i  = mask_row[i];

    // Region boundaries (diff monotone non-decreasing in j) + mask-ones count:
    //   jlo  = #{j : diff <= -BINS}  -> j <  jlo  : idx==1  (vlo)
    //   jend = #{j : diff <   BINS}  -> j >= jend : idx==65 (vhi)
    {
        int c1 = 0, c2 = 0, cm = 0;
        for (int j = tid; j < L_; j += 256) {
            const int diff = ridx_row[j] - ri_i;
            c1 += (diff <= -BINS);
            c2 += (diff <   BINS);
            cm += (mask_row[j] != 0.0f);
        }
        for (int off = 32; off; off >>= 1) {   // wave64 reduce -> 1 atomic set/wave
            c1 += __shfl_down(c1, off);
            c2 += __shfl_down(c2, off);
            cm += __shfl_down(cm, off);
        }
        if ((tid & 63) == 0) {
            atomicAdd(&s_cnt[0], c1);
            atomicAdd(&s_cnt[1], c2);
            atomicAdd(&s_cnt[2], cm);
        }
    }
    __syncthreads();

    const int  jlo  = s_cnt[0];
    const int  jend = s_cnt[1];
    const bool fast = (s_cnt[2] == L_) && (m_i == 1.0f);  // all masks == 1

    float* rowout = out + (size_t)row * L_ * CZ;   // contiguous 384 KB row
    // Group g handles j == g (mod 8) in every region -> a wave's two groups
    // always write adjacent j's = 1 KB contiguous per wave store-pair.
    const int jb0 = jlo  + ((group - jlo ) & 7);
    const int jh0 = jend + ((group - jend) & 7);

    if (fast) {
        // Pure register-constant NT store streams: no loads, no L2 allocate.
        #pragma unroll 8
        for (int j = group; j < jlo; j += 8)
            nt_store(rowout + j * CZ + 4 * lane, vlo);
        #pragma unroll 2
        for (int j = jb0; j < jend; j += 8) {      // band: ~48 j's per row
            const int diff = ridx_row[j] - ri_i;
            const int idx  = min(max(diff, -BINS), BINS) + BINS + 1;
            nt_store(rowout + j * CZ + 4 * lane, W4[idx * (CZ / 4) + lane] + b4);
        }
        #pragma unroll 8
        for (int j = jh0; j < L_; j += 8)
            nt_store(rowout + j * CZ + 4 * lane, vhi);
    } else {
        // General path: per-j mask product.
        #pragma unroll 4
        for (int j = group; j < jlo; j += 8)
            nt_store(rowout + j * CZ + 4 * lane, vlo * (m_i * mask_row[j]));
        #pragma unroll 2
        for (int j = jb0; j < jend; j += 8) {
            const int diff = ridx_row[j] - ri_i;
            const int idx  = min(max(diff, -BINS), BINS) + BINS + 1;
            vfloat4 v = W4[idx * (CZ / 4) + lane] + b4;
            nt_store(rowout + j * CZ + 4 * lane, v * (m_i * mask_row[j]));
        }
        #pragma unroll 4
        for (int j = jh0; j < L_; j += 8)
            nt_store(rowout + j * CZ + 4 * lane, vhi * (m_i * mask_row[j]));
    }
}

extern "C" void kernel_launch(void* const* d_in, const int* in_sizes, int n_in,
                              void* d_out, int out_size, void* d_ws, size_t ws_size,
                              hipStream_t stream) {
    const int*  residue_index = (const int*)d_in[0];
    const void* residue_mask  = d_in[1];
    const float* W    = (const float*)d_in[2];
    const float* bias = (const float*)d_in[3];
    float* out = (float*)d_out;

    relpos_kernel<<<NBLK, 256, 0, stream>>>(residue_index, residue_mask, W, bias, out);
}